// Round 5
// baseline (73.013 us; speedup 1.0000x reference)
//
#include <hip/hip_runtime.h>

// SourcePE: out[n,b,e] = dropout( emb[n,b,e] + sin(box[b,n,e&3] * den[e>>2]) )
// dropout mask = JAX threefry2x32, key(42)=(0,42), partitionable path:
//   bits(i) = out0 ^ out1 of threefry((0,42), (0, i))
//   keep <=> bits < 7549747*512 = 3865470464   (bit-exact, verified R1-R4)
//
// R5: R4 pipeline base (71.6us) + (a) 2 groups/thread/iter (streams g and
// g+HALF: shared den, halved loop overhead, 2x independent hash ILP),
// (b) v_sin direct with 1/2pi pre-folded into den, (c) explicit add3-fused
// key injections + folded round 1 (x0 starts at 0).

namespace {

typedef float f32x4 __attribute__((ext_vector_type(4)));

constexpr int      NBOX     = 1024;
constexpr unsigned TOTAL_G  = 1024u * 64u * 128u;  // 8388608 float4-groups
constexpr unsigned HALF_G   = TOTAL_G / 2u;        // 4194304
constexpr unsigned NBLK     = 2048;                // 8 blocks/CU co-resident
constexpr unsigned NTHR     = 256;
constexpr unsigned STRIDE_G = NBLK * NTHR;         // 524288
constexpr int      ITERS    = HALF_G / STRIDE_G;   // 8
// per-thread: j = g&127 invariant; row advances +4096/iter => n += 64/iter.
// stream B = stream A + HALF_G: same j, same b, nB = nA + 512.

__device__ __forceinline__ unsigned rotl(unsigned x, int r) {
  return __builtin_amdgcn_alignbit(x, x, 32 - r);  // 1-op rotate
}

// threefry2x32, key=(0,42): ks0=0, ks1=42, ks2=0x1BD11BDA^42=0x1BD11BF0
// Injection fusion: {x0+=ksA; x1+=ksB; x0+=x1} == {x1+=ksB; x0=x0+x1+ksA}.
__device__ __forceinline__ unsigned threefry_xor(unsigned ctr) {
  unsigned x1 = ctr + 42u;                 // ctr_lo + ks1
  unsigned x0 = x1;                        // round 1: x0 = 0 + x1
  x1 = rotl(x1,13) ^ x0;
  x0 += x1; x1 = rotl(x1,15) ^ x0;
  x0 += x1; x1 = rotl(x1,26) ^ x0;
  x0 += x1; x1 = rotl(x1, 6) ^ x0;
  x1 += 0x1BD11BF1u;                       // inj1: ks2+1
  x0 = x0 + x1 + 42u;                      // inj1: ks1, fused w/ round-5 add
  x1 = rotl(x1,17) ^ x0;
  x0 += x1; x1 = rotl(x1,29) ^ x0;
  x0 += x1; x1 = rotl(x1,16) ^ x0;
  x0 += x1; x1 = rotl(x1,24) ^ x0;
  x1 += 2u;                                // inj2: ks0+2
  x0 = x0 + x1 + 0x1BD11BF0u;              // inj2: ks2, fused
  x1 = rotl(x1,13) ^ x0;
  x0 += x1; x1 = rotl(x1,15) ^ x0;
  x0 += x1; x1 = rotl(x1,26) ^ x0;
  x0 += x1; x1 = rotl(x1, 6) ^ x0;
  x1 += 45u;                               // inj3: ks1+3 (ks0=0 side free)
  x0 += x1;
  x1 = rotl(x1,17) ^ x0;
  x0 += x1; x1 = rotl(x1,29) ^ x0;
  x0 += x1; x1 = rotl(x1,16) ^ x0;
  x0 += x1; x1 = rotl(x1,24) ^ x0;
  x1 += 0x1BD11BF4u;                       // inj4: ks2+4
  x0 = x0 + x1 + 42u;                      // inj4: ks1, fused
  x1 = rotl(x1,13) ^ x0;
  x0 += x1; x1 = rotl(x1,15) ^ x0;
  x0 += x1; x1 = rotl(x1,26) ^ x0;
  x0 += x1; x1 = rotl(x1, 6) ^ x0;
  return (x0 + 0x1BD11BF0u) ^ (x1 + 5u);   // inj5: ks2 / ks0+5, then combine
}

__device__ __forceinline__ f32x4 body(const f32x4 e, const int4 bx,
                                      const float den_rev, const unsigned i0) {
  const float SC = 1.11111111111111111f;  // 1/0.9
  // den_rev has 1/(2pi) folded in: v_sin takes revolutions.
  const float s0 = __builtin_amdgcn_sinf((float)bx.x * den_rev);
  const float s1 = __builtin_amdgcn_sinf((float)bx.y * den_rev);
  const float s2 = __builtin_amdgcn_sinf((float)bx.z * den_rev);
  const float s3 = __builtin_amdgcn_sinf((float)bx.w * den_rev);

  const unsigned m0 = threefry_xor(i0);
  const unsigned m1 = threefry_xor(i0 + 1u);
  const unsigned m2 = threefry_xor(i0 + 2u);
  const unsigned m3 = threefry_xor(i0 + 3u);

  f32x4 r;
  r.x = (m0 < 3865470464u) ? (e.x + s0) * SC : 0.0f;
  r.y = (m1 < 3865470464u) ? (e.y + s1) * SC : 0.0f;
  r.z = (m2 < 3865470464u) ? (e.z + s2) * SC : 0.0f;
  r.w = (m3 < 3865470464u) ? (e.w + s3) * SC : 0.0f;
  return r;
}

__global__ __launch_bounds__(256) void pe_add_dropout(
    const f32x4* __restrict__ emb,
    const int4*  __restrict__ boxes,
    f32x4*       __restrict__ out) {
  const float K2     = 0.0064881408103268795f;   // log2(10000)/2048
  const float INV2PI = 0.15915494309189535f;

  const unsigned g0   = blockIdx.x * NTHR + threadIdx.x;  // < 524288
  const unsigned j    = g0 & 127u;
  const unsigned row0 = g0 >> 7;            // < 4096
  const unsigned b    = row0 & 63u;
  const unsigned n0   = row0 >> 6;          // < 32

  const float den_rev = exp2f(-(float)j * K2) * INV2PI;  // hoisted

  const f32x4* epA = emb + g0;
  const f32x4* epB = epA + HALF_G;
  const int4*  bpA = boxes + (b * NBOX + n0);
  const int4*  bpB = bpA + 512;             // nB = nA + 512
  f32x4*       opA = out + g0;
  f32x4*       opB = opA + HALF_G;
  unsigned     i0A = g0 << 2;               // flat element index, stream A
  // stream B counter = i0A + HALF_G*4 = i0A + 16777216

  // prologue: load iteration 0
  f32x4 eA = *epA, eB = *epB;

#pragma unroll 2
  for (int it = 0; it < ITERS - 1; ++it) {
    const int4 bxA = *bpA;
    const int4 bxB = *bpB;
    // prefetch next iteration's emb (in-bounds: it+1 <= ITERS-1)
    epA += STRIDE_G;  epB += STRIDE_G;
    const f32x4 eA_nx = *epA;
    const f32x4 eB_nx = *epB;

    *opA = body(eA, bxA, den_rev, i0A);
    *opB = body(eB, bxB, den_rev, i0A + 16777216u);

    bpA += 64;  bpB += 64;                 // n += 64
    opA += STRIDE_G;  opB += STRIDE_G;
    i0A += STRIDE_G * 4u;
    eA = eA_nx;  eB = eB_nx;
  }
  // epilogue: last iteration, no prefetch
  const int4 bxA = *bpA;
  const int4 bxB = *bpB;
  *opA = body(eA, bxA, den_rev, i0A);
  *opB = body(eB, bxB, den_rev, i0A + 16777216u);
}

}  // namespace

extern "C" void kernel_launch(void* const* d_in, const int* in_sizes, int n_in,
                              void* d_out, int out_size, void* d_ws, size_t ws_size,
                              hipStream_t stream) {
  const f32x4* emb   = (const f32x4*)d_in[0];  // (1024, 64, 512) f32
  const int4*  boxes = (const int4*)d_in[1];   // (64, 1024, 4) i32
  f32x4*       outp  = (f32x4*)d_out;          // (1024, 64, 512) f32
  hipLaunchKernelGGL(pe_add_dropout, dim3(NBLK), dim3(NTHR), 0, stream,
                     emb, boxes, outp);
}

// Round 6
// 70.749 us; speedup vs baseline: 1.0320x; 1.0320x over previous
//
#include <hip/hip_runtime.h>

// SourcePE: out[n,b,e] = dropout( emb[n,b,e] + sin(box[b,n,e&3] * den[e>>2]) )
// dropout mask = JAX threefry2x32, key(42)=(0,42), partitionable path:
//   bits(i) = out0 ^ out1 of threefry((0,42), (0, i))
//   keep <=> bits < 7549747*512 = 3865470464   (bit-exact, verified R1-R5)
//
// R6 = R4 (best: 71.6us; 2-deep pipeline, pointer-increment) with ONE change:
// grid 2048 -> 4096 blocks (2x oversubscription). R5's op-shave+2-stream ILP
// was neutral => not op-bound; testing the occupancy/ramp hypothesis
// (R3's 8192-block run showed Occupancy 75% vs 50% at 2048 blocks).

namespace {

typedef float f32x4 __attribute__((ext_vector_type(4)));

constexpr int      NBOX     = 1024;
constexpr unsigned TOTAL_G  = 1024u * 64u * 128u;  // 8388608 float4-groups
constexpr unsigned NBLK     = 4096;                // 2x machine capacity
constexpr unsigned NTHR     = 256;
constexpr unsigned STRIDE_G = NBLK * NTHR;         // 1048576 groups
constexpr int      ITERS    = TOTAL_G / STRIDE_G;  // 8
// per-thread: j = g&127 invariant, b invariant, n += 128 per iter.

__device__ __forceinline__ unsigned rotl(unsigned x, int r) {
  return __builtin_amdgcn_alignbit(x, x, 32 - r);  // 1-op rotate
}

// threefry2x32, key=(0,42): ks0=0, ks1=42, ks2=0x1BD11BDA^42=0x1BD11BF0
__device__ __forceinline__ unsigned threefry_xor(unsigned ctr) {
  unsigned x0 = 0u;          // ctr_hi + ks0
  unsigned x1 = ctr + 42u;   // ctr_lo + ks1
#define R4(a,b,c,d)                       \
  x0 += x1; x1 = rotl(x1,(a)) ^ x0;       \
  x0 += x1; x1 = rotl(x1,(b)) ^ x0;       \
  x0 += x1; x1 = rotl(x1,(c)) ^ x0;       \
  x0 += x1; x1 = rotl(x1,(d)) ^ x0;
  R4(13,15,26,6)
  x0 += 42u;          x1 += 0x1BD11BF1u;  // ks1, ks2+1
  R4(17,29,16,24)
  x0 += 0x1BD11BF0u;  x1 += 2u;           // ks2, ks0+2
  R4(13,15,26,6)
  /* ks0 = 0 */       x1 += 45u;          // ks1+3
  R4(17,29,16,24)
  x0 += 42u;          x1 += 0x1BD11BF4u;  // ks1, ks2+4
  R4(13,15,26,6)
  x0 += 0x1BD11BF0u;  x1 += 5u;           // ks2, ks0+5
#undef R4
  return x0 ^ x1;
}

__device__ __forceinline__ f32x4 body(const f32x4 e, const int4 bx,
                                      const float den, const unsigned i0) {
  const float SC = 1.11111111111111111f;  // 1/0.9
  const float s0 = __sinf((float)bx.x * den);
  const float s1 = __sinf((float)bx.y * den);
  const float s2 = __sinf((float)bx.z * den);
  const float s3 = __sinf((float)bx.w * den);

  const unsigned m0 = threefry_xor(i0);
  const unsigned m1 = threefry_xor(i0 + 1u);
  const unsigned m2 = threefry_xor(i0 + 2u);
  const unsigned m3 = threefry_xor(i0 + 3u);

  f32x4 r;
  r.x = (m0 < 3865470464u) ? (e.x + s0) * SC : 0.0f;
  r.y = (m1 < 3865470464u) ? (e.y + s1) * SC : 0.0f;
  r.z = (m2 < 3865470464u) ? (e.z + s2) * SC : 0.0f;
  r.w = (m3 < 3865470464u) ? (e.w + s3) * SC : 0.0f;
  return r;
}

__global__ __launch_bounds__(256) void pe_add_dropout(
    const f32x4* __restrict__ emb,
    const int4*  __restrict__ boxes,
    f32x4*       __restrict__ out) {
  const float K2 = 0.0064881408103268795f;  // log2(10000)/2048

  const unsigned g0   = blockIdx.x * NTHR + threadIdx.x;  // < 1048576
  const unsigned j    = g0 & 127u;
  const unsigned row0 = g0 >> 7;            // n*64 + b, < 8192
  const unsigned b    = row0 & 63u;
  const unsigned n0   = row0 >> 6;          // < 128

  const float den = exp2f(-(float)j * K2); // hoisted: j invariant

  const f32x4* ep = emb + g0;
  const int4*  bp = boxes + (b * NBOX + n0);
  f32x4*       op = out + g0;
  unsigned     i0 = g0 << 2;               // flat element index

  // prologue: load iteration 0
  f32x4 e  = *ep;
  int4  bx = *bp;

#pragma unroll 3
  for (int it = 0; it < ITERS - 1; ++it) {
    // prefetch next iteration (in-bounds: it+1 <= ITERS-1)
    ep += STRIDE_G;
    bp += 128;                             // n += 128
    const f32x4 e_nx = *ep;
    const int4  b_nx = *bp;

    *op = body(e, bx, den, i0);

    op += STRIDE_G;
    i0 += STRIDE_G * 4u;
    e  = e_nx;
    bx = b_nx;
  }
  // epilogue: last iteration, no prefetch
  *op = body(e, bx, den, i0);
}

}  // namespace

extern "C" void kernel_launch(void* const* d_in, const int* in_sizes, int n_in,
                              void* d_out, int out_size, void* d_ws, size_t ws_size,
                              hipStream_t stream) {
  const f32x4* emb   = (const f32x4*)d_in[0];  // (1024, 64, 512) f32
  const int4*  boxes = (const int4*)d_in[1];   // (64, 1024, 4) i32
  f32x4*       outp  = (f32x4*)d_out;          // (1024, 64, 512) f32
  hipLaunchKernelGGL(pe_add_dropout, dim3(NBLK), dim3(NTHR), 0, stream,
                     emb, boxes, outp);
}

// Round 7
// 69.372 us; speedup vs baseline: 1.0525x; 1.0198x over previous
//
#include <hip/hip_runtime.h>

// SourcePE: out[n,b,e] = dropout( emb[n,b,e] + sin(box[b,n,e&3] * den[e>>2]) )
// dropout mask = JAX threefry2x32, key(42)=(0,42), partitionable path:
//   bits(i) = out0 ^ out1 of threefry((0,42), (0, i))
//   keep <=> bits < 7549747*512 = 3865470464   (bit-exact, verified R1-R6)
//
// R7 = R6 base (best: 70.7us; 4096 blocks, pointer-increment) with ONE
// change: software-pipeline depth 2 -> 4 (prefetch 3 iters ahead ~1920cy,
// covering the ~900cy HBM miss latency that a 1-iter-ahead prefetch ~640cy
// does not). Rotating 4-slot register buffer, fully unrolled so all buffer
// indices are compile-time constants (no scratch).

namespace {

typedef float f32x4 __attribute__((ext_vector_type(4)));

constexpr int      NBOX     = 1024;
constexpr unsigned TOTAL_G  = 1024u * 64u * 128u;  // 8388608 float4-groups
constexpr unsigned NBLK     = 4096;
constexpr unsigned NTHR     = 256;
constexpr unsigned STRIDE_G = NBLK * NTHR;         // 1048576 groups
constexpr int      ITERS    = TOTAL_G / STRIDE_G;  // 8
constexpr int      PFD      = 3;                   // prefetch distance (iters)
// per-thread: j = g&127 invariant, b invariant, n += 128 per iter.

__device__ __forceinline__ unsigned rotl(unsigned x, int r) {
  return __builtin_amdgcn_alignbit(x, x, 32 - r);  // 1-op rotate
}

// threefry2x32, key=(0,42): ks0=0, ks1=42, ks2=0x1BD11BDA^42=0x1BD11BF0
__device__ __forceinline__ unsigned threefry_xor(unsigned ctr) {
  unsigned x0 = 0u;          // ctr_hi + ks0
  unsigned x1 = ctr + 42u;   // ctr_lo + ks1
#define R4(a,b,c,d)                       \
  x0 += x1; x1 = rotl(x1,(a)) ^ x0;       \
  x0 += x1; x1 = rotl(x1,(b)) ^ x0;       \
  x0 += x1; x1 = rotl(x1,(c)) ^ x0;       \
  x0 += x1; x1 = rotl(x1,(d)) ^ x0;
  R4(13,15,26,6)
  x0 += 42u;          x1 += 0x1BD11BF1u;  // ks1, ks2+1
  R4(17,29,16,24)
  x0 += 0x1BD11BF0u;  x1 += 2u;           // ks2, ks0+2
  R4(13,15,26,6)
  /* ks0 = 0 */       x1 += 45u;          // ks1+3
  R4(17,29,16,24)
  x0 += 42u;          x1 += 0x1BD11BF4u;  // ks1, ks2+4
  R4(13,15,26,6)
  x0 += 0x1BD11BF0u;  x1 += 5u;           // ks2, ks0+5
#undef R4
  return x0 ^ x1;
}

__device__ __forceinline__ f32x4 body(const f32x4 e, const int4 bx,
                                      const float den, const unsigned i0) {
  const float SC = 1.11111111111111111f;  // 1/0.9
  const float s0 = __sinf((float)bx.x * den);
  const float s1 = __sinf((float)bx.y * den);
  const float s2 = __sinf((float)bx.z * den);
  const float s3 = __sinf((float)bx.w * den);

  const unsigned m0 = threefry_xor(i0);
  const unsigned m1 = threefry_xor(i0 + 1u);
  const unsigned m2 = threefry_xor(i0 + 2u);
  const unsigned m3 = threefry_xor(i0 + 3u);

  f32x4 r;
  r.x = (m0 < 3865470464u) ? (e.x + s0) * SC : 0.0f;
  r.y = (m1 < 3865470464u) ? (e.y + s1) * SC : 0.0f;
  r.z = (m2 < 3865470464u) ? (e.z + s2) * SC : 0.0f;
  r.w = (m3 < 3865470464u) ? (e.w + s3) * SC : 0.0f;
  return r;
}

__global__ __launch_bounds__(256) void pe_add_dropout(
    const f32x4* __restrict__ emb,
    const int4*  __restrict__ boxes,
    f32x4*       __restrict__ out) {
  const float K2 = 0.0064881408103268795f;  // log2(10000)/2048

  const unsigned g0   = blockIdx.x * NTHR + threadIdx.x;  // < 1048576
  const unsigned j    = g0 & 127u;
  const unsigned row0 = g0 >> 7;            // n*64 + b, < 8192
  const unsigned b    = row0 & 63u;
  const unsigned n0   = row0 >> 6;          // < 128

  const float den = exp2f(-(float)j * K2); // hoisted: j invariant

  const f32x4* ep = emb + g0;
  const int4*  bp = boxes + (b * NBOX + n0);
  f32x4*       op = out + g0;
  unsigned     i0 = g0 << 2;               // flat element index

  // 4-slot rotating register buffer; prologue loads iters 0..PFD-1
  f32x4 ebuf[4];
  int4  xbuf[4];
#pragma unroll
  for (int k = 0; k < PFD; ++k) {
    ebuf[k] = ep[(unsigned)k * STRIDE_G];
    xbuf[k] = bp[k * 128];
  }

#pragma unroll
  for (int it = 0; it < ITERS; ++it) {
    // issue prefetch for iteration it+PFD (constant condition under unroll)
    if (it + PFD < ITERS) {
      ebuf[(it + PFD) & 3] = ep[(unsigned)(it + PFD) * STRIDE_G];
      xbuf[(it + PFD) & 3] = bp[(it + PFD) * 128];
    }
    op[(unsigned)it * STRIDE_G] =
        body(ebuf[it & 3], xbuf[it & 3], den, i0 + (unsigned)it * (STRIDE_G * 4u));
  }
}

}  // namespace

extern "C" void kernel_launch(void* const* d_in, const int* in_sizes, int n_in,
                              void* d_out, int out_size, void* d_ws, size_t ws_size,
                              hipStream_t stream) {
  const f32x4* emb   = (const f32x4*)d_in[0];  // (1024, 64, 512) f32
  const int4*  boxes = (const int4*)d_in[1];   // (64, 1024, 4) i32
  f32x4*       outp  = (f32x4*)d_out;          // (1024, 64, 512) f32
  hipLaunchKernelGGL(pe_add_dropout, dim3(NBLK), dim3(NTHR), 0, stream,
                     emb, boxes, outp);
}